// Round 8
// baseline (410.928 us; speedup 1.0000x reference)
//
#include <hip/hip_runtime.h>
#include <hip/hip_bf16.h>
#include <stdint.h>

// out = x @ W'^T + bias, W' = FWHT(W rows)/sqrt(n)  (H symmetric, folded into W)
// x (4,2048,8192) f32 -> M=8192, K=8192 ; W (2048,8192) -> N=2048 ; out f32.

#define M_TOTAL 8192
#define K_TOTAL 8192
#define N_TOTAL 2048
#define D_IN 8192

typedef __attribute__((ext_vector_type(8))) short short8;
typedef __attribute__((ext_vector_type(4))) float f32x4;

typedef __attribute__((address_space(1))) void void_g;
typedef __attribute__((address_space(3))) void void_l;
typedef __attribute__((address_space(3))) short lds_s3;

__device__ __forceinline__ short f2bf(float f) {
  __hip_bfloat16 h = __float2bfloat16(f);
  return *reinterpret_cast<short*>(&h);
}

// ---------------- kernel 1: x fp32 -> bf16 ----------------
__global__ void cvt_x_kernel(const float* __restrict__ x, short* __restrict__ xb, long n) {
  long stride = (long)gridDim.x * blockDim.x * 8;
  for (long i = ((long)blockIdx.x * blockDim.x + threadIdx.x) * 8; i < n; i += stride) {
    float4 v0 = *(const float4*)(x + i);
    float4 v1 = *(const float4*)(x + i + 4);
    short8 o;
    o[0] = f2bf(v0.x); o[1] = f2bf(v0.y); o[2] = f2bf(v0.z); o[3] = f2bf(v0.w);
    o[4] = f2bf(v1.x); o[5] = f2bf(v1.y); o[6] = f2bf(v1.z); o[7] = f2bf(v1.w);
    *(short8*)(xb + i) = o;
  }
}

// ---------------- kernel 2: W' = FWHT(W rows) / sqrt(n), bf16 ----------------
__global__ void fwht_w_kernel(const float* __restrict__ W, short* __restrict__ Wh) {
  __shared__ float buf[D_IN];
  const int row = blockIdx.x;
  const float* src = W + (long)row * D_IN;
  for (int i = threadIdx.x; i < D_IN / 4; i += blockDim.x)
    ((float4*)buf)[i] = ((const float4*)src)[i];
  for (int h = 1; h < D_IN; h <<= 1) {
    __syncthreads();
    for (int p = threadIdx.x; p < D_IN / 2; p += blockDim.x) {
      int i = ((p & ~(h - 1)) << 1) | (p & (h - 1));
      float a = buf[i], b = buf[i + h];
      buf[i] = a + b;
      buf[i + h] = a - b;
    }
  }
  __syncthreads();
  const float s = 0.011048543456039806f; // 1/sqrt(8192)
  short* dst = Wh + (long)row * D_IN;
  for (int i = threadIdx.x; i < D_IN; i += blockDim.x)
    dst[i] = f2bf(buf[i] * s);
}

// ---------------- kernel 3: 256x256 8-phase bf16 GEMM (m201 port, asm ds_read) --
// Identical schedule/layout to R7 (38% MfmaUtil) EXCEPT fragment reads are
// opaque inline-asm ds_read_b128. Theory: compiler-visible LDS reads make
// SIInsertWaitcnts insert vmcnt(0) against outstanding global_load_lds DMA
// (alias conservatism) -> hidden per-phase full drain -> latency exposure.
// Opaque reads remove that; ordering is manual: lgkmcnt + sched_barrier(0)
// immediately before each MFMA cluster (rule #18).
#define NT 128 // K-tiles of 64

#define ADST(D, H) (((D) * 2 + (H)) * 8192 + sdst)
#define BDST(D, H) (32768 + ((D) * 2 + (H)) * 8192 + sdst)

#define STG(DST, SRC, KOFF)                                                                       \
  __builtin_amdgcn_global_load_lds((void_g*)((SRC) + (KOFF)), (void_l*)&lds[DST], 16, 0, 0);      \
  __builtin_amdgcn_global_load_lds((void_g*)((SRC) + (KOFF) + 32), (void_l*)&lds[(DST) + 4096],   \
                                   16, 0, 0);

#define DSR(dst, ADDR, IMM)                                                                       \
  asm volatile("ds_read_b128 %0, %1 offset:%2" : "=v"(dst) : "v"(ADDR), "i"(IMM))

// A frag (mi,ks) byte offset: ks*8192 + (MIB+mi)*256 ; B frag (nj,ks): ks*8192 + nj*256
#define RD_A4(AD, MIB)                                                                            \
  DSR(am[0][0], AD, (MIB) * 256 + 0);   DSR(am[0][1], AD, (MIB) * 256 + 8192);                    \
  DSR(am[1][0], AD, (MIB) * 256 + 256); DSR(am[1][1], AD, (MIB) * 256 + 8448);                    \
  DSR(am[2][0], AD, (MIB) * 256 + 512); DSR(am[2][1], AD, (MIB) * 256 + 8704);                    \
  DSR(am[3][0], AD, (MIB) * 256 + 768); DSR(am[3][1], AD, (MIB) * 256 + 8960);

#define RD_B2(BD, NJB)                                                                            \
  DSR(bn[(NJB)][0], BD, (NJB) * 256 + 0);       DSR(bn[(NJB)][1], BD, (NJB) * 256 + 8192);        \
  DSR(bn[(NJB) + 1][0], BD, (NJB) * 256 + 256); DSR(bn[(NJB) + 1][1], BD, (NJB) * 256 + 8448);

#define MF(MIB, NJB)                                                                              \
  __builtin_amdgcn_s_setprio(1);                                                                  \
  _Pragma("unroll") for (int mi = 0; mi < 4; ++mi) {                                              \
    _Pragma("unroll") for (int nj = 0; nj < 2; ++nj) {                                            \
      _Pragma("unroll") for (int ks = 0; ks < 2; ++ks) acc[(MIB) + mi][(NJB) + nj] =              \
          __builtin_amdgcn_mfma_f32_16x16x32_bf16(am[mi][ks], bn[(NJB) + nj][ks],                 \
                                                  acc[(MIB) + mi][(NJB) + nj], 0, 0, 0);          \
    }                                                                                             \
  }                                                                                               \
  __builtin_amdgcn_s_setprio(0);

#define BAR __builtin_amdgcn_s_barrier()
#define SBAR __builtin_amdgcn_sched_barrier(0)
#define LG0 do { asm volatile("s_waitcnt lgkmcnt(0)"); SBAR; } while (0)

// one K-tile (4 phases). D: dbuf 0/1; STGA/STGB bools; KA/KB k-offsets (shorts);
// FN "4"/"0"; DOF: emit vmcnt fence; LB: trailing barrier.
#define KTILE(D, STGA, KA, STGB, KB, FN, DOF, LB)                                                 \
  {                                                                                               \
    /* ph1: quadrant (mi0-3 x nj0-1) */                                                           \
    RD_B2(bAd[D], 0);                                                                             \
    RD_A4(aAd[D], 0);                                                                             \
    if (STGA) { STG(ADST(D ^ 1, 0), aSrc0, KA); }                                                 \
    asm volatile("s_waitcnt lgkmcnt(8)");                                                         \
    BAR;                                                                                          \
    LG0;                                                                                          \
    MF(0, 0);                                                                                     \
    BAR;                                                                                          \
    /* ph2: (mi0-3 x nj2-3) */                                                                    \
    RD_B2(bAd[D], 2);                                                                             \
    if (STGA) { STG(ADST(D ^ 1, 1), aSrc1, KA); }                                                 \
    BAR;                                                                                          \
    LG0;                                                                                          \
    MF(0, 2);                                                                                     \
    BAR;                                                                                          \
    /* ph3: (mi4-7 x nj0-1) */                                                                    \
    RD_A4(aAd[D], 4);                                                                             \
    if (STGB) { STG(BDST(D, 0), bSrc0, KB); }                                                     \
    BAR;                                                                                          \
    LG0;                                                                                          \
    MF(4, 0);                                                                                     \
    BAR;                                                                                          \
    /* ph4: (mi4-7 x nj2-3), fence */                                                             \
    if (STGB) { STG(BDST(D, 1), bSrc1, KB); }                                                     \
    BAR;                                                                                          \
    MF(4, 2);                                                                                     \
    if (DOF) { asm volatile("s_waitcnt vmcnt(" FN ")"); }                                         \
    if (LB) BAR;                                                                                  \
  }

__global__ __launch_bounds__(512, 2) void gemm_kernel(const short* __restrict__ A,
                                                      const short* __restrict__ B,
                                                      const float* __restrict__ bias,
                                                      float* __restrict__ C) {
  __shared__ __attribute__((aligned(16))) short lds[65536]; // 128 KiB

  const int tid = threadIdx.x;
  const int l = tid & 63;
  const int w = tid >> 6;
  const int wm = w >> 2;   // 0..1 (M half)
  const int wn = w & 3;    // 0..3 (N quarter)
  const int wh = wn >> 1;  // B half
  const int w1 = wn & 1;   // within B half

  // XCD-aware bijective swizzle (nwg = 256)
  const int bid = blockIdx.x;
  const int swz = (bid & 7) * 32 + (bid >> 3);
  const int bm = swz >> 3;
  const int bn_ = swz & 7;
  const long tileM = (long)bm * 256;
  const long tileN = (long)bn_ * 256;

  // fragment read base addresses (bytes, LDS address space)
  const int lanepart = (l >> 4) * 1024 + (l & 15) * 8; // shorts
  const unsigned ldsbase = (unsigned)(uintptr_t)(lds_s3*)&lds[0];
  unsigned aAd[2], bAd[2];
  aAd[0] = ldsbase + (unsigned)((0 * 2 + wm) * 8192 + lanepart) * 2u;
  aAd[1] = ldsbase + (unsigned)((1 * 2 + wm) * 8192 + lanepart) * 2u;
  bAd[0] = ldsbase + (unsigned)(32768 + (0 * 2 + wh) * 8192 + lanepart + w1 * 512) * 2u;
  bAd[1] = ldsbase + (unsigned)(32768 + (1 * 2 + wh) * 8192 + lanepart + w1 * 512) * 2u;

  // staging: thread -> (row = tid&127, kchunk = tid>>7); dest = halfbase + tid*8 (+4096)
  const int sdst = tid * 8;
  const short* aSrc0 = A + (tileM + 0 * 128 + (tid & 127)) * (long)K_TOTAL + (tid >> 7) * 8;
  const short* aSrc1 = A + (tileM + 1 * 128 + (tid & 127)) * (long)K_TOTAL + (tid >> 7) * 8;
  const short* bSrc0 = B + (tileN + 0 * 128 + (tid & 127)) * (long)K_TOTAL + (tid >> 7) * 8;
  const short* bSrc1 = B + (tileN + 1 * 128 + (tid & 127)) * (long)K_TOTAL + (tid >> 7) * 8;

  f32x4 acc[8][4];
#pragma unroll
  for (int mi = 0; mi < 8; ++mi)
#pragma unroll
    for (int nj = 0; nj < 4; ++nj)
      acc[mi][nj] = (f32x4){0.f, 0.f, 0.f, 0.f};

  // prologue: A(0), B(0) into d0; B(1) into d1 (12 loads); vmcnt(4) leaves B(1)
  STG(ADST(0, 0), aSrc0, 0);
  STG(ADST(0, 1), aSrc1, 0);
  STG(BDST(0, 0), bSrc0, 0);
  STG(BDST(0, 1), bSrc1, 0);
  STG(BDST(1, 0), bSrc0, 64);
  STG(BDST(1, 1), bSrc1, 64);
  asm volatile("s_waitcnt vmcnt(4)");
  BAR;

  short8 am[4][2], bn[4][2];

  // main: t = 0,2,...,124; sub-d0 stages A(t+1), B(t+2); sub-d1 stages A(t+2), B(t+3)
  for (int t = 0; t < NT - 2; t += 2) {
    KTILE(0, true, (t + 1) * 64, true, (t + 2) * 64, "4", true, true);
    KTILE(1, true, (t + 2) * 64, true, (t + 3) * 64, "4", true, true);
  }
  // tail: t = 126 stages A(127) only, drains; t = 127 compute-only
  KTILE(0, true, 127 * 64, false, 0, "0", true, true);
  KTILE(1, false, 0, false, 0, "0", false, false);

  // epilogue: C = acc + bias
  const int rb = (int)tileM + wm * 128 + (l >> 4) * 4;
  const int cb = (int)tileN + wn * 64 + (l & 15);
#pragma unroll
  for (int mi = 0; mi < 8; ++mi)
#pragma unroll
    for (int nj = 0; nj < 4; ++nj) {
      float bv = bias[cb + nj * 16];
      const int r0 = rb + mi * 16;
#pragma unroll
      for (int r = 0; r < 4; ++r)
        C[(long)(r0 + r) * N_TOTAL + cb + nj * 16] = acc[mi][nj][r] + bv;
    }
}

extern "C" void kernel_launch(void* const* d_in, const int* in_sizes, int n_in,
                              void* d_out, int out_size, void* d_ws, size_t ws_size,
                              hipStream_t stream) {
  const float* x = (const float*)d_in[0];
  const float* W = (const float*)d_in[1];
  const float* bias = (const float*)d_in[2];
  float* out = (float*)d_out;

  short* xb = (short*)d_ws;                                          // 134 MB
  short* wh = (short*)((char*)d_ws + (size_t)M_TOTAL * K_TOTAL * 2); // 33.5 MB

  cvt_x_kernel<<<2048, 256, 0, stream>>>(x, xb, (long)M_TOTAL * K_TOTAL);
  fwht_w_kernel<<<N_TOTAL, 256, 0, stream>>>(W, wh);

  const int grid = (M_TOTAL / 256) * (N_TOTAL / 256); // 256
  gemm_kernel<<<grid, 512, 0, stream>>>(xb, wh, bias, out);
}

// Round 10
// 364.205 us; speedup vs baseline: 1.1283x; 1.1283x over previous
//
#include <hip/hip_runtime.h>
#include <hip/hip_bf16.h>
#include <stdint.h>

// out = x @ W'^T + bias, W' = FWHT(W rows)/sqrt(n)  (H symmetric, folded into W)
// x (4,2048,8192) f32 -> M=8192, K=8192 ; W (2048,8192) -> N=2048 ; out f32.

#define M_TOTAL 8192
#define K_TOTAL 8192
#define N_TOTAL 2048
#define D_IN 8192

typedef __attribute__((ext_vector_type(8))) short short8;
typedef __attribute__((ext_vector_type(4))) float f32x4;

typedef __attribute__((address_space(1))) void void_g;
typedef __attribute__((address_space(3))) void void_l;
typedef __attribute__((address_space(3))) short lds_s3;

__device__ __forceinline__ short f2bf(float f) {
  __hip_bfloat16 h = __float2bfloat16(f);
  return *reinterpret_cast<short*>(&h);
}

// ---------------- kernel 1: x fp32 -> bf16 ----------------
__global__ void cvt_x_kernel(const float* __restrict__ x, short* __restrict__ xb, long n) {
  long stride = (long)gridDim.x * blockDim.x * 8;
  for (long i = ((long)blockIdx.x * blockDim.x + threadIdx.x) * 8; i < n; i += stride) {
    float4 v0 = *(const float4*)(x + i);
    float4 v1 = *(const float4*)(x + i + 4);
    short8 o;
    o[0] = f2bf(v0.x); o[1] = f2bf(v0.y); o[2] = f2bf(v0.z); o[3] = f2bf(v0.w);
    o[4] = f2bf(v1.x); o[5] = f2bf(v1.y); o[6] = f2bf(v1.z); o[7] = f2bf(v1.w);
    *(short8*)(xb + i) = o;
  }
}

// ---------------- kernel 2: W' = FWHT(W rows) / sqrt(n), bf16 ----------------
__global__ void fwht_w_kernel(const float* __restrict__ W, short* __restrict__ Wh) {
  __shared__ float buf[D_IN];
  const int row = blockIdx.x;
  const float* src = W + (long)row * D_IN;
  for (int i = threadIdx.x; i < D_IN / 4; i += blockDim.x)
    ((float4*)buf)[i] = ((const float4*)src)[i];
  for (int h = 1; h < D_IN; h <<= 1) {
    __syncthreads();
    for (int p = threadIdx.x; p < D_IN / 2; p += blockDim.x) {
      int i = ((p & ~(h - 1)) << 1) | (p & (h - 1));
      float a = buf[i], b = buf[i + h];
      buf[i] = a + b;
      buf[i + h] = a - b;
    }
  }
  __syncthreads();
  const float s = 0.011048543456039806f; // 1/sqrt(8192)
  short* dst = Wh + (long)row * D_IN;
  for (int i = threadIdx.x; i < D_IN; i += blockDim.x)
    dst[i] = f2bf(buf[i] * s);
}

// ---------------- kernel 3: 256x256, BK=32, free-run 4-ring bf16 GEMM -----------
// 512 thr = 8 waves (2M x 4N). Tiles [256 rows][32 k] bf16 row-major (64B/row),
// XOR swizzle: 16B slot s stored at s ^ ((row>>1)&3). Staging: thread t ->
// LDS linear t*16B (row t>>2 / slot t&3), global source slot (t&3)^((t>>3)&3):
// per wave 16 rows x full 64B row -> COALESCED. Read side applies same XOR ->
// 2 lanes/slot = free. LDS ring: 4 bufs x (A 16KB + B 16KB) = 128 KiB. ONE
// fused {vmcnt(4); s_barrier} per K-tile: waves free-run across the 32-MFMA
// tile body so the LDS-read drain overlaps MFMA across waves. All 12 next-tile
// frag reads pre-issued at tile end (asm ds_read; lgkmcnt(0)+sched_barrier at
// tile start per rule 18). Ledger: stage t+3 in tile t; end-of-t fence
// vmcnt(4) validates tile t+2 (one tile before its preload at t+1... read at
// t+2).  *** R9 BUG FIX: 256 K-tiles (BK=32), not 128 — loop bound 252 and
// tail stage KOFF 255*32 (R9 computed only half of K: absmax 3.7 = N(0,0.5)
// max-stat over 16.8M outputs). ***
#define NKT 256 // K-tiles of 32

#define ABUF(b) ((b) * 8192)
#define BBUF(b) (32768 + (b) * 8192)

#define SBAR __builtin_amdgcn_sched_barrier(0)
#define BAR __builtin_amdgcn_s_barrier()
#define LG0 do { asm volatile("s_waitcnt lgkmcnt(0)"); SBAR; } while (0)
#define FEN4 do { SBAR; asm volatile("s_waitcnt vmcnt(4)"); BAR; } while (0)
#define FEN0 do { SBAR; asm volatile("s_waitcnt vmcnt(0)"); BAR; } while (0)

// stage one K-tile (A + B, 4 x global_load_lds w16 per thread)
#define STAGET(PB, KOFF)                                                                          \
  __builtin_amdgcn_global_load_lds((void_g*)(aLo + (KOFF)),                                       \
                                   (void_l*)&lds[ABUF(PB) + sdst], 16, 0, 0);                     \
  __builtin_amdgcn_global_load_lds((void_g*)(aHi + (KOFF)),                                       \
                                   (void_l*)&lds[ABUF(PB) + sdst + 4096], 16, 0, 0);              \
  __builtin_amdgcn_global_load_lds((void_g*)(bLo + (KOFF)),                                       \
                                   (void_l*)&lds[BBUF(PB) + sdst], 16, 0, 0);                     \
  __builtin_amdgcn_global_load_lds((void_g*)(bHi + (KOFF)),                                       \
                                   (void_l*)&lds[BBUF(PB) + sdst + 4096], 16, 0, 0);

#define DSR(dst, ADDR, IMM)                                                                       \
  asm volatile("ds_read_b128 %0, %1 offset:%2" : "=v"(dst) : "v"(ADDR), "i"(IMM))

// pre-issue all 12 frag reads for buffer NB (tile t+1)
#define PRELOAD(NB)                                                                               \
  DSR(bn[0], bAdr, (NB) * 16384 + 0);    DSR(bn[1], bAdr, (NB) * 16384 + 1024);                   \
  DSR(bn[2], bAdr, (NB) * 16384 + 2048); DSR(bn[3], bAdr, (NB) * 16384 + 3072);                   \
  DSR(am[0], aAdr, (NB) * 16384 + 0);    DSR(am[1], aAdr, (NB) * 16384 + 1024);                   \
  DSR(am[2], aAdr, (NB) * 16384 + 2048); DSR(am[3], aAdr, (NB) * 16384 + 3072);                   \
  DSR(am[4], aAdr, (NB) * 16384 + 4096); DSR(am[5], aAdr, (NB) * 16384 + 5120);                   \
  DSR(am[6], aAdr, (NB) * 16384 + 6144); DSR(am[7], aAdr, (NB) * 16384 + 7168);

#define MFQ(MIB)                                                                                  \
  __builtin_amdgcn_s_setprio(1);                                                                  \
  _Pragma("unroll") for (int mi = 0; mi < 4; ++mi) {                                              \
    _Pragma("unroll") for (int nj = 0; nj < 4; ++nj)                                              \
        acc[(MIB) + mi][nj] = __builtin_amdgcn_mfma_f32_16x16x32_bf16(                            \
            am[(MIB) + mi], bn[nj], acc[(MIB) + mi][nj], 0, 0, 0);                                \
  }                                                                                               \
  __builtin_amdgcn_s_setprio(0);

// one K-tile: wait pre-issued frags; Q1 (mi0-3); stage t+3; Q2 (mi4-7);
// pre-issue t+1 frags; single fence.
#define KT(DOSTG, PB, KOFF, DOPRE, NB, DOF4, DOF0)                                                \
  {                                                                                               \
    LG0;                                                                                          \
    MFQ(0);                                                                                       \
    if (DOSTG) { STAGET(PB, KOFF); }                                                              \
    MFQ(4);                                                                                       \
    if (DOPRE) { PRELOAD(NB); }                                                                   \
    if (DOF4) FEN4;                                                                               \
    if (DOF0) FEN0;                                                                               \
  }

__global__ __launch_bounds__(512, 2) void gemm_kernel(const short* __restrict__ A,
                                                      const short* __restrict__ B,
                                                      const float* __restrict__ bias,
                                                      float* __restrict__ C) {
  __shared__ __attribute__((aligned(16))) short lds[65536]; // 128 KiB

  const int tid = threadIdx.x;
  const int l = tid & 63;
  const int w = tid >> 6;
  const int wm = w >> 2;  // 0..1 (M half: rows wm*128..)
  const int wn = w & 3;   // 0..3 (N quarter: rows wn*64..)

  // XCD-aware bijective swizzle (nwg = 256)
  const int bid = blockIdx.x;
  const int swz = (bid & 7) * 32 + (bid >> 3);
  const int bm = swz >> 3;
  const int bn_ = swz & 7;
  const long tileM = (long)bm * 256;
  const long tileN = (long)bn_ * 256;

  // fragment read addresses: row = (wave rows) + (l&15); k-slot = l>>4, stored
  // at slot ^ ((row>>1)&3) = slot ^ ((l>>1)&3)  (row low bits come from l&15)
  const int kx = (((l >> 4) ^ ((l >> 1) & 3)) * 8); // shorts
  const int rb = (l & 15) * 32;                     // shorts
  const unsigned ldsbase = (unsigned)(uintptr_t)(lds_s3*)&lds[0];
  const unsigned aAdr = ldsbase + (unsigned)(wm * 4096 + rb + kx) * 2u;
  const unsigned bAdr = ldsbase + (unsigned)(32768 + wn * 2048 + rb + kx) * 2u;

  // staging: thread t -> LDS t*16B (+8KB for rows 128..255); global source
  // row = t>>2 (and +128), k-slot = (t&3) ^ ((t>>3)&3)  [key=(row>>1)&3]
  const int sdst = tid * 8; // shorts
  const int sslot = ((tid & 3) ^ ((tid >> 3) & 3)) * 8;
  const short* aLo = A + (tileM + (tid >> 2)) * (long)K_TOTAL + sslot;
  const short* aHi = aLo + 128 * (long)K_TOTAL;
  const short* bLo = B + (tileN + (tid >> 2)) * (long)K_TOTAL + sslot;
  const short* bHi = bLo + 128 * (long)K_TOTAL;

  f32x4 acc[8][4];
#pragma unroll
  for (int mi = 0; mi < 8; ++mi)
#pragma unroll
    for (int nj = 0; nj < 4; ++nj)
      acc[mi][nj] = (f32x4){0.f, 0.f, 0.f, 0.f};

  short8 am[8], bn[4];

  // prologue: stage tiles 0,1,2 (12 loads); vmcnt(4) drains 0,1; pre-issue tile 0
  STAGET(0, 0);
  STAGET(1, 32);
  STAGET(2, 64);
  SBAR;
  asm volatile("s_waitcnt vmcnt(4)");
  BAR;
  PRELOAD(0);

  // main: t = 0..251 (stages tiles 3..254)
  for (int t4 = 0; t4 < 252; t4 += 4) {
    KT(true, 3, (t4 + 3) * 32, true, 1, true, false);
    KT(true, 0, (t4 + 4) * 32, true, 2, true, false);
    KT(true, 1, (t4 + 5) * 32, true, 3, true, false);
    KT(true, 2, (t4 + 6) * 32, true, 0, true, false);
  }
  // t=252: stage tile 255 (validates 254); t=253: drain (validates 255);
  // t=254: preload tile 255; t=255: compute only
  KT(true, 3, 255 * 32, true, 1, true, false);
  KT(false, 0, 0, true, 2, false, true);
  KT(false, 0, 0, true, 3, false, false);
  KT(false, 0, 0, false, 0, false, false);

  // epilogue: C = acc + bias  (C/D map: col = l&15, row = (l>>4)*4 + reg)
  const int rb0 = (int)tileM + wm * 128 + (l >> 4) * 4;
  const int cb = (int)tileN + wn * 64 + (l & 15);
#pragma unroll
  for (int mi = 0; mi < 8; ++mi)
#pragma unroll
    for (int nj = 0; nj < 4; ++nj) {
      float bv = bias[cb + nj * 16];
      const int r0 = rb0 + mi * 16;
#pragma unroll
      for (int r = 0; r < 4; ++r)
        C[(long)(r0 + r) * N_TOTAL + cb + nj * 16] = acc[mi][nj][r] + bv;
    }
}

extern "C" void kernel_launch(void* const* d_in, const int* in_sizes, int n_in,
                              void* d_out, int out_size, void* d_ws, size_t ws_size,
                              hipStream_t stream) {
  const float* x = (const float*)d_in[0];
  const float* W = (const float*)d_in[1];
  const float* bias = (const float*)d_in[2];
  float* out = (float*)d_out;

  short* xb = (short*)d_ws;                                          // 134 MB
  short* wh = (short*)((char*)d_ws + (size_t)M_TOTAL * K_TOTAL * 2); // 33.5 MB

  cvt_x_kernel<<<2048, 256, 0, stream>>>(x, xb, (long)M_TOTAL * K_TOTAL);
  fwht_w_kernel<<<N_TOTAL, 256, 0, stream>>>(W, wh);

  const int grid = (M_TOTAL / 256) * (N_TOTAL / 256); // 256
  gemm_kernel<<<grid, 512, 0, stream>>>(xb, wh, bias, out);
}

// Round 11
// 363.005 us; speedup vs baseline: 1.1320x; 1.0033x over previous
//
#include <hip/hip_runtime.h>
#include <hip/hip_bf16.h>
#include <stdint.h>

// out = x @ W'^T + bias, W' = FWHT(W rows)/sqrt(n)  (H symmetric, folded into W)
// x (4,2048,8192) f32 -> M=8192, K=8192 ; W (2048,8192) -> N=2048 ; out f32.

#define M_TOTAL 8192
#define K_TOTAL 8192
#define N_TOTAL 2048
#define D_IN 8192

typedef __attribute__((ext_vector_type(8))) short short8;
typedef __attribute__((ext_vector_type(4))) float f32x4;

typedef __attribute__((address_space(1))) void void_g;
typedef __attribute__((address_space(3))) void void_l;
typedef __attribute__((address_space(3))) short lds_s3;

__device__ __forceinline__ short f2bf(float f) {
  __hip_bfloat16 h = __float2bfloat16(f);
  return *reinterpret_cast<short*>(&h);
}

// ---------------- kernel 1: x fp32 -> bf16 ----------------
__global__ void cvt_x_kernel(const float* __restrict__ x, short* __restrict__ xb, long n) {
  long stride = (long)gridDim.x * blockDim.x * 8;
  for (long i = ((long)blockIdx.x * blockDim.x + threadIdx.x) * 8; i < n; i += stride) {
    float4 v0 = *(const float4*)(x + i);
    float4 v1 = *(const float4*)(x + i + 4);
    short8 o;
    o[0] = f2bf(v0.x); o[1] = f2bf(v0.y); o[2] = f2bf(v0.z); o[3] = f2bf(v0.w);
    o[4] = f2bf(v1.x); o[5] = f2bf(v1.y); o[6] = f2bf(v1.z); o[7] = f2bf(v1.w);
    *(short8*)(xb + i) = o;
  }
}

// ---------------- kernel 2: W' = FWHT(W rows) / sqrt(n), bf16 ----------------
__global__ void fwht_w_kernel(const float* __restrict__ W, short* __restrict__ Wh) {
  __shared__ float buf[D_IN];
  const int row = blockIdx.x;
  const float* src = W + (long)row * D_IN;
  for (int i = threadIdx.x; i < D_IN / 4; i += blockDim.x)
    ((float4*)buf)[i] = ((const float4*)src)[i];
  for (int h = 1; h < D_IN; h <<= 1) {
    __syncthreads();
    for (int p = threadIdx.x; p < D_IN / 2; p += blockDim.x) {
      int i = ((p & ~(h - 1)) << 1) | (p & (h - 1));
      float a = buf[i], b = buf[i + h];
      buf[i] = a + b;
      buf[i + h] = a - b;
    }
  }
  __syncthreads();
  const float s = 0.011048543456039806f; // 1/sqrt(8192)
  short* dst = Wh + (long)row * D_IN;
  for (int i = threadIdx.x; i < D_IN; i += blockDim.x)
    dst[i] = f2bf(buf[i] * s);
}

// ---------------- kernel 3: 256x256, BK=32, free-run 4-ring bf16 GEMM -----------
// R10 structure (coalesced XOR-swizzled staging, 4-deep ring, ONE fused
// {vmcnt(4); s_barrier} per K-tile) which measured 1127 TF / 50.5% MfmaUtil.
// R11 change: next-tile ds_reads issued INSIDE the tile body (not at tile end)
// so the CU-wide DS drain (~750 cy) overlaps the MFMA stream (~1242 cy/SIMD)
// instead of serializing after it. Legal because the end-of-(t-1) fence already
// validated buffer t+1 at tile-t start, and each read's dest register is dead
// at its issue point (am[0..3] after MFQ0, bn/am[4..7] after MFQ4) -> zero
// extra VGPRs. Counted lgkm ledger per tile (DS in-order per wave):
//   entry: outstanding = am03(t),bn(t),am47(t) [12] -> lgkm(4): am03+bn ready
//   MFQ0(am03,bn); issue am03(t+1) [<=8 outstanding] -> lgkm(4): am47(t) ready
//   MFQ4(am47,bn); issue bn(t+1)+am47(t+1) [12]; fence vmcnt(4)+barrier.
#define NKT 256 // K-tiles of 32

#define ABUF(b) ((b) * 8192)
#define BBUF(b) (32768 + (b) * 8192)

#define SBAR __builtin_amdgcn_sched_barrier(0)
#define BAR __builtin_amdgcn_s_barrier()
#define FEN4 do { SBAR; asm volatile("s_waitcnt vmcnt(4)"); BAR; } while (0)
#define FEN0 do { SBAR; asm volatile("s_waitcnt vmcnt(0)"); BAR; } while (0)
#define FNOP do { } while (0)

// stage one K-tile (A + B, 4 x global_load_lds w16 per thread)
#define STAGET(PB, KOFF)                                                                          \
  __builtin_amdgcn_global_load_lds((void_g*)(aLo + (KOFF)),                                       \
                                   (void_l*)&lds[ABUF(PB) + sdst], 16, 0, 0);                     \
  __builtin_amdgcn_global_load_lds((void_g*)(aHi + (KOFF)),                                       \
                                   (void_l*)&lds[ABUF(PB) + sdst + 4096], 16, 0, 0);              \
  __builtin_amdgcn_global_load_lds((void_g*)(bLo + (KOFF)),                                       \
                                   (void_l*)&lds[BBUF(PB) + sdst], 16, 0, 0);                     \
  __builtin_amdgcn_global_load_lds((void_g*)(bHi + (KOFF)),                                       \
                                   (void_l*)&lds[BBUF(PB) + sdst + 4096], 16, 0, 0);

#define DSR(dst, ADDR, IMM)                                                                       \
  asm volatile("ds_read_b128 %0, %1 offset:%2" : "=v"(dst) : "v"(ADDR), "i"(IMM))

// issue groups for buffer NB (next tile). Steady-state issue order per tile:
// AM03 (mid-tile), BN + AM47 (tile end) -> entry lgkm(4) = {am03,bn} done.
#define RD_AM03(NB)                                                                               \
  DSR(am[0], aAdr, (NB) * 16384 + 0);    DSR(am[1], aAdr, (NB) * 16384 + 1024);                   \
  DSR(am[2], aAdr, (NB) * 16384 + 2048); DSR(am[3], aAdr, (NB) * 16384 + 3072);
#define RD_BN(NB)                                                                                 \
  DSR(bn[0], bAdr, (NB) * 16384 + 0);    DSR(bn[1], bAdr, (NB) * 16384 + 1024);                   \
  DSR(bn[2], bAdr, (NB) * 16384 + 2048); DSR(bn[3], bAdr, (NB) * 16384 + 3072);
#define RD_AM47(NB)                                                                               \
  DSR(am[4], aAdr, (NB) * 16384 + 4096); DSR(am[5], aAdr, (NB) * 16384 + 5120);                   \
  DSR(am[6], aAdr, (NB) * 16384 + 6144); DSR(am[7], aAdr, (NB) * 16384 + 7168);

#define MFQ(MIB)                                                                                  \
  __builtin_amdgcn_s_setprio(1);                                                                  \
  _Pragma("unroll") for (int mi = 0; mi < 4; ++mi) {                                              \
    _Pragma("unroll") for (int nj = 0; nj < 4; ++nj)                                              \
        acc[(MIB) + mi][nj] = __builtin_amdgcn_mfma_f32_16x16x32_bf16(                            \
            am[(MIB) + mi], bn[nj], acc[(MIB) + mi][nj], 0, 0, 0);                                \
  }                                                                                               \
  __builtin_amdgcn_s_setprio(0);

// one K-tile. DOSTG: stage tile t+3 into slot PB. DOPRE: issue next-tile reads
// (buffer NB). FEN: end fence (FEN4 / FEN0 / FNOP).
#define KT(DOSTG, PB, KOFF, DOPRE, NB, FEN)                                                       \
  {                                                                                               \
    asm volatile("s_waitcnt lgkmcnt(4)");                                                         \
    SBAR;                                                                                         \
    MFQ(0);                                                                                       \
    SBAR;                                                                                         \
    if (DOSTG) { STAGET(PB, KOFF); }                                                              \
    if (DOPRE) { RD_AM03(NB); }                                                                   \
    SBAR;                                                                                         \
    if (DOPRE) { asm volatile("s_waitcnt lgkmcnt(4)"); }                                          \
    else       { asm volatile("s_waitcnt lgkmcnt(0)"); }                                          \
    SBAR;                                                                                         \
    MFQ(4);                                                                                       \
    SBAR;                                                                                         \
    if (DOPRE) { RD_BN(NB); RD_AM47(NB); }                                                        \
    SBAR;                                                                                        \
    FEN;                                                                                          \
  }

__global__ __launch_bounds__(512, 2) void gemm_kernel(const short* __restrict__ A,
                                                      const short* __restrict__ B,
                                                      const float* __restrict__ bias,
                                                      float* __restrict__ C) {
  __shared__ __attribute__((aligned(16))) short lds[65536]; // 128 KiB

  const int tid = threadIdx.x;
  const int l = tid & 63;
  const int w = tid >> 6;
  const int wm = w >> 2;  // 0..1 (M half: rows wm*128..)
  const int wn = w & 3;   // 0..3 (N quarter: rows wn*64..)

  // XCD-aware bijective swizzle (nwg = 256)
  const int bid = blockIdx.x;
  const int swz = (bid & 7) * 32 + (bid >> 3);
  const int bm = swz >> 3;
  const int bn_ = swz & 7;
  const long tileM = (long)bm * 256;
  const long tileN = (long)bn_ * 256;

  // fragment read addresses: row = (wave rows) + (l&15); k-slot = l>>4, stored
  // at slot ^ ((row>>1)&3) = slot ^ ((l>>1)&3)
  const int kx = (((l >> 4) ^ ((l >> 1) & 3)) * 8); // shorts
  const int rb = (l & 15) * 32;                     // shorts
  const unsigned ldsbase = (unsigned)(uintptr_t)(lds_s3*)&lds[0];
  const unsigned aAdr = ldsbase + (unsigned)(wm * 4096 + rb + kx) * 2u;
  const unsigned bAdr = ldsbase + (unsigned)(32768 + wn * 2048 + rb + kx) * 2u;

  // staging: thread t -> LDS t*16B (+8KB for rows 128..255); global source
  // row = t>>2 (and +128), k-slot = (t&3) ^ ((t>>3)&3)  [key=(row>>1)&3]
  const int sdst = tid * 8; // shorts
  const int sslot = ((tid & 3) ^ ((tid >> 3) & 3)) * 8;
  const short* aLo = A + (tileM + (tid >> 2)) * (long)K_TOTAL + sslot;
  const short* aHi = aLo + 128 * (long)K_TOTAL;
  const short* bLo = B + (tileN + (tid >> 2)) * (long)K_TOTAL + sslot;
  const short* bHi = bLo + 128 * (long)K_TOTAL;

  f32x4 acc[8][4];
#pragma unroll
  for (int mi = 0; mi < 8; ++mi)
#pragma unroll
    for (int nj = 0; nj < 4; ++nj)
      acc[mi][nj] = (f32x4){0.f, 0.f, 0.f, 0.f};

  short8 am[8], bn[4];

  // prologue: stage tiles 0,1,2; vmcnt(4) validates 0,1; barrier; issue tile-0
  // reads in steady-state order (am03, bn, am47)
  STAGET(0, 0);
  STAGET(1, 32);
  STAGET(2, 64);
  SBAR;
  asm volatile("s_waitcnt vmcnt(4)");
  BAR;
  RD_AM03(0);
  RD_BN(0);
  RD_AM47(0);
  SBAR;

  // main: t = 0..251 (stages tiles 3..254; preloads buffer (t+1)&3)
  for (int t4 = 0; t4 < 252; t4 += 4) {
    KT(true, 3, (t4 + 3) * 32, true, 1, FEN4);
    KT(true, 0, (t4 + 4) * 32, true, 2, FEN4);
    KT(true, 1, (t4 + 5) * 32, true, 3, FEN4);
    KT(true, 2, (t4 + 6) * 32, true, 0, FEN4);
  }
  // t=252: stage 255 (fence validates <=254); t=253: FEN0 validates 255;
  // t=254: preload 255, no fence; t=255: compute only (lgkm(0) mid-tile)
  KT(true, 3, 255 * 32, true, 1, FEN4);
  KT(false, 0, 0, true, 2, FEN0);
  KT(false, 0, 0, true, 3, FNOP);
  KT(false, 0, 0, false, 0, FNOP);

  // epilogue: C = acc + bias  (C/D map: col = l&15, row = (l>>4)*4 + reg)
  const int rb0 = (int)tileM + wm * 128 + (l >> 4) * 4;
  const int cb = (int)tileN + wn * 64 + (l & 15);
#pragma unroll
  for (int mi = 0; mi < 8; ++mi)
#pragma unroll
    for (int nj = 0; nj < 4; ++nj) {
      float bv = bias[cb + nj * 16];
      const int r0 = rb0 + mi * 16;
#pragma unroll
      for (int r = 0; r < 4; ++r)
        C[(long)(r0 + r) * N_TOTAL + cb + nj * 16] = acc[mi][nj][r] + bv;
    }
}

extern "C" void kernel_launch(void* const* d_in, const int* in_sizes, int n_in,
                              void* d_out, int out_size, void* d_ws, size_t ws_size,
                              hipStream_t stream) {
  const float* x = (const float*)d_in[0];
  const float* W = (const float*)d_in[1];
  const float* bias = (const float*)d_in[2];
  float* out = (float*)d_out;

  short* xb = (short*)d_ws;                                          // 134 MB
  short* wh = (short*)((char*)d_ws + (size_t)M_TOTAL * K_TOTAL * 2); // 33.5 MB

  cvt_x_kernel<<<2048, 256, 0, stream>>>(x, xb, (long)M_TOTAL * K_TOTAL);
  fwht_w_kernel<<<N_TOTAL, 256, 0, stream>>>(W, wh);

  const int grid = (M_TOTAL / 256) * (N_TOTAL / 256); // 256
  gemm_kernel<<<grid, 512, 0, stream>>>(xb, wh, bias, out);
}